// Round 6
// baseline (134.416 us; speedup 1.0000x reference)
//
#include <hip/hip_runtime.h>
#include <hip/hip_bf16.h>

#define E_ 8
#define B_ 8
#define S_ 2048
#define D_ 512
#define R_ 128
#define M_TOT (B_ * S_)   // 16384

typedef __attribute__((ext_vector_type(8))) short bf16x8;
typedef __attribute__((ext_vector_type(4))) float f32x4;

__device__ __forceinline__ void gload_lds16(void* lds, const void* g) {
  __builtin_amdgcn_global_load_lds(
      (const __attribute__((address_space(1))) void*)g,
      (__attribute__((address_space(3))) void*)lds, 16, 0, 0);
}

// ---------------------------------------------------------------------------
// Fused prep kernel. Grid roles (rot first so its serial chains start early):
//   [0,16)           rotation recurrence: W[e] cols 0..128, 256 rows/block
//   [16,2064)        W tail cols 129..511 = bf16(proj_w)
//   [2064,6160)      x f32 -> bf16 (2 float4 groups per thread)
// ---------------------------------------------------------------------------
#define ROT_B 16
#define WT_B 2048
#define CX_B 4096
__global__ __launch_bounds__(256) void prep_fused(
    const float* __restrict__ x, const float* __restrict__ theta,
    const float* __restrict__ pw, __hip_bfloat16* __restrict__ xb,
    __hip_bfloat16* __restrict__ Wb) {
  int blk = blockIdx.x;
  int t = threadIdx.x;
  if (blk < ROT_B) {
    // ---- rotation: all Givens planes are (0,k+1) -> per-row recurrence ----
    __shared__ float cs[R_], ss[R_];
    __shared__ float Pch[256][17];            // 17-stride: conflict-free
    __shared__ __hip_bfloat16 Wch[256][18];
    int e = blk >> 1;
    int r0 = (blk & 1) * 256;
    if (t < R_) {
      float a = tanhf(theta[e * R_ + t]) * 0.1f;
      cs[t] = cosf(a);
      ss[t] = sinf(a);
    }
    const float* Pe = pw + (size_t)e * D_ * D_;
    __hip_bfloat16* We = Wb + (size_t)e * D_ * D_;
    float u = Pe[(size_t)(r0 + t) * D_];  // P[r][0]
    __syncthreads();
    for (int c = 0; c < 8; ++c) {  // 16 k-columns per chunk
      for (int i = t; i < 256 * 16; i += 256) {
        int row = i >> 4, col = i & 15;
        Pch[row][col] = Pe[(size_t)(r0 + row) * D_ + 1 + 16 * c + col];
      }
      __syncthreads();
#pragma unroll
      for (int kk = 0; kk < 16; ++kk) {
        int k = 16 * c + kk;
        float pj = Pch[t][kk];
        Wch[t][kk] = __float2bfloat16(cs[k] * pj - ss[k] * u);
        u = cs[k] * u + ss[k] * pj;
      }
      __syncthreads();
      for (int i = t; i < 256 * 16; i += 256) {
        int row = i >> 4, col = i & 15;
        We[(size_t)(r0 + row) * D_ + 1 + 16 * c + col] = Wch[row][col];
      }
      __syncthreads();
    }
    We[(size_t)(r0 + t) * D_] = __float2bfloat16(u);
  } else if (blk < ROT_B + WT_B) {
    // ---- W tail: cols 129..511 ----
    int g = (blk - ROT_B) * 256 + t;   // group over E*D*D/4
    int gidx = g & 127;                // d = gidx*4 .. +3
    if (gidx < 32) return;             // d <= 127 owned by rotation
    float4 v = ((const float4*)pw)[g];
    union { short4 s; __hip_bfloat16 h[4]; } u;
    u.h[0] = __float2bfloat16(v.x);
    u.h[1] = __float2bfloat16(v.y);
    u.h[2] = __float2bfloat16(v.z);
    u.h[3] = __float2bfloat16(v.w);
    if (gidx > 32) {
      ((short4*)Wb)[g] = u.s;
    } else {  // d = 128..131 -> write 129..131 only
      Wb[(size_t)g * 4 + 1] = u.h[1];
      Wb[(size_t)g * 4 + 2] = u.h[2];
      Wb[(size_t)g * 4 + 3] = u.h[3];
    }
  } else {
    // ---- x conversion: 2 float4 groups per thread ----
    int i = (blk - ROT_B - WT_B) * 256 + t;
#pragma unroll
    for (int rep = 0; rep < 2; ++rep) {
      int idx = i + rep * (CX_B * 256);
      float4 v = ((const float4*)x)[idx];
      union { short4 s; __hip_bfloat16 h[4]; } u;
      u.h[0] = __float2bfloat16(v.x);
      u.h[1] = __float2bfloat16(v.y);
      u.h[2] = __float2bfloat16(v.z);
      u.h[3] = __float2bfloat16(v.w);
      ((short4*)xb)[idx] = u.s;
    }
  }
}

// ---------------------------------------------------------------------------
// GEMM: out[e] = Xb @ Wb[e]^T  (NT). Write-bound regime (256MB out vs 27us
// ideal MFMA) -> many small staggered blocks so writes stream continuously.
// 128x128 tile, BK=32, 4 waves (2x2), 2-slot LDS ring (32 KB -> ~3 blocks/CU
// with VGPR<=168). Counted vmcnt: stage t+1 BEFORE waiting for t ->
// wait vmcnt(4) never drains the pipe (T4). Involutive chunk swizzle on
// staging-source + fragment-read (T2, conflict-free). setprio (T5).
// XCD swizzle (T1): 32 consecutive blocks share one A-panel, W L2-resident.
// ---------------------------------------------------------------------------
__global__ __launch_bounds__(256, 3) void gemm_xw(
    const __hip_bfloat16* __restrict__ Xb,   // [M_TOT][512]
    const __hip_bfloat16* __restrict__ Wb,   // [E][512][512] rows=o, cols=d
    float* __restrict__ out)                 // [E][M_TOT][512]
{
  constexpr int BM = 128, BN = 128, BK = 32;
  constexpr int KD = D_, ND = D_;
  constexpr int NT = KD / BK;  // 16
  __shared__ __align__(16) __hip_bfloat16 As[2][BM * BK];  // 16 KB
  __shared__ __align__(16) __hip_bfloat16 Bs[2][BN * BK];  // 16 KB

  // T1: bijective XCD-chunked swizzle; within an XCD: nt fastest, then e,
  // then mt -> 32 consecutive blocks share one A panel and sweep W (L2-fit).
  int bx = blockIdx.x;                 // 4096 blocks, 4096%8==0
  int swz = (bx & 7) * 512 + (bx >> 3);
  int mt = swz >> 5;          // 0..127
  int e  = (swz >> 2) & 7;    // 0..7
  int nt = swz & 3;           // 0..3

  int tid = threadIdx.x;
  int wave = tid >> 6, lane = tid & 63;
  int lr = lane & 15, lk = lane >> 4;
  int wm = wave >> 1, wn = wave & 1;   // 2x2 waves, each owns 64x64 of C

  const __hip_bfloat16* Ag = Xb + (size_t)(mt * BM) * KD;
  const __hip_bfloat16* Bg = Wb + ((size_t)e * ND + (size_t)nt * BN) * KD;

  // staging source: row = lane>>2, 16B chunk permuted within the row's 64B
  int srow = lane >> 2;
  int scol = ((lane & 3) ^ ((lane >> 3) & 3)) * 8;
  // fragment read: chunk slot = lk ^ ((row>>1)&3)
  int cterm = (lk ^ ((lr >> 1) & 3)) * 8;
  int aoff = (wm * 64 + lr) * BK + cterm;
  int boff = (wn * 64 + lr) * BK + cterm;

  f32x4 acc[4][4];
#pragma unroll
  for (int i = 0; i < 4; ++i)
#pragma unroll
    for (int j = 0; j < 4; ++j) acc[i][j] = (f32x4){0.f, 0.f, 0.f, 0.f};

  // stage tile t into slot: wave covers rows [wave*32, +32), 2 issues
#define STAGE(slot, t)                                                       \
  {                                                                          \
    _Pragma("unroll") for (int i = 0; i < 2; ++i) {                          \
      int rbase = wave * 32 + i * 16;                                        \
      gload_lds16(&As[slot][rbase * BK],                                     \
                  Ag + (size_t)(rbase + srow) * KD + (t) * BK + scol);       \
      gload_lds16(&Bs[slot][rbase * BK],                                     \
                  Bg + (size_t)(rbase + srow) * KD + (t) * BK + scol);       \
    }                                                                        \
  }

  STAGE(0, 0);
#pragma unroll
  for (int t = 0; t < NT; ++t) {
    int slot = t & 1;
    if (t + 1 < NT) {
      STAGE(slot ^ 1, t + 1);  // issue BEFORE wait: keeps 4 loads in flight
      asm volatile("s_waitcnt vmcnt(4)" ::: "memory");  // tile t landed
    } else {
      asm volatile("s_waitcnt vmcnt(0)" ::: "memory");
    }
    __builtin_amdgcn_s_barrier();        // tile t visible to all waves
    asm volatile("" ::: "memory");
    bf16x8 bfr[4], af[4];
#pragma unroll
    for (int ni = 0; ni < 4; ++ni)
      bfr[ni] = *(const bf16x8*)&Bs[slot][boff + ni * 16 * BK];
#pragma unroll
    for (int mi = 0; mi < 4; ++mi)
      af[mi] = *(const bf16x8*)&As[slot][aoff + mi * 16 * BK];
    __builtin_amdgcn_s_setprio(1);
#pragma unroll
    for (int mi = 0; mi < 4; ++mi)
#pragma unroll
      for (int ni = 0; ni < 4; ++ni)
        acc[mi][ni] = __builtin_amdgcn_mfma_f32_16x16x32_bf16(
            af[mi], bfr[ni], acc[mi][ni], 0, 0, 0);
    __builtin_amdgcn_s_setprio(0);
    asm volatile("" ::: "memory");
    __builtin_amdgcn_s_barrier();        // done reading slot before restage
    asm volatile("" ::: "memory");
  }
#undef STAGE

  // epilogue: C/D layout col = lane&15, row = (lane>>4)*4 + reg  [m89]
  size_t obase = (size_t)e * M_TOT * ND;
  int row0 = mt * BM + wm * 64;
  int col0 = nt * BN + wn * 64;
#pragma unroll
  for (int mi = 0; mi < 4; ++mi)
#pragma unroll
    for (int ni = 0; ni < 4; ++ni) {
      int r0 = row0 + mi * 16 + lk * 4;
      int c = col0 + ni * 16 + lr;
      float* op = out + obase + (size_t)r0 * ND + c;
#pragma unroll
      for (int q = 0; q < 4; ++q) op[(size_t)q * ND] = acc[mi][ni][q];
    }
}

extern "C" void kernel_launch(void* const* d_in, const int* in_sizes, int n_in,
                              void* d_out, int out_size, void* d_ws, size_t ws_size,
                              hipStream_t stream) {
  const float* x = (const float*)d_in[0];        // [B][S][D] f32
  const float* theta = (const float*)d_in[1];    // [E][R] f32
  const float* proj_w = (const float*)d_in[2];   // [E][D][D] f32
  float* out = (float*)d_out;                    // [E][B][S][D] f32

  __hip_bfloat16* xb = (__hip_bfloat16*)d_ws;                          // 16 MB
  __hip_bfloat16* Wb = (__hip_bfloat16*)((char*)d_ws +
                        (size_t)M_TOT * D_ * sizeof(__hip_bfloat16));  // 4 MB

  hipLaunchKernelGGL(prep_fused, dim3(ROT_B + WT_B + CX_B), dim3(256), 0,
                     stream, x, theta, proj_w, xb, Wb);
  hipLaunchKernelGGL(gemm_xw, dim3(E_ * (M_TOT / 128) * (D_ / 128)), dim3(256),
                     0, stream, xb, Wb, out);
}

// Round 7
// 128.083 us; speedup vs baseline: 1.0494x; 1.0494x over previous
//
#include <hip/hip_runtime.h>
#include <hip/hip_bf16.h>

#define E_ 8
#define B_ 8
#define S_ 2048
#define D_ 512
#define R_ 128
#define M_TOT (B_ * S_)   // 16384

typedef __attribute__((ext_vector_type(8))) short bf16x8;
typedef __attribute__((ext_vector_type(4))) float f32x4;

__device__ __forceinline__ void gload_lds16(void* lds, const void* g) {
  __builtin_amdgcn_global_load_lds(
      (const __attribute__((address_space(1))) void*)g,
      (__attribute__((address_space(3))) void*)lds, 16, 0, 0);
}

// ---------------------------------------------------------------------------
// Fused prep kernel (unchanged from R5, the best-so-far):
//   [0,16)           rotation recurrence: W[e] cols 0..128
//   [16,2064)        W tail cols 129..511 = bf16(proj_w)
//   [2064,6160)      x f32 -> bf16
// ---------------------------------------------------------------------------
#define ROT_B 16
#define WT_B 2048
#define CX_B 4096
__global__ __launch_bounds__(256) void prep_fused(
    const float* __restrict__ x, const float* __restrict__ theta,
    const float* __restrict__ pw, __hip_bfloat16* __restrict__ xb,
    __hip_bfloat16* __restrict__ Wb) {
  int blk = blockIdx.x;
  int t = threadIdx.x;
  if (blk < ROT_B) {
    __shared__ float cs[R_], ss[R_];
    __shared__ float Pch[256][17];
    __shared__ __hip_bfloat16 Wch[256][18];
    int e = blk >> 1;
    int r0 = (blk & 1) * 256;
    if (t < R_) {
      float a = tanhf(theta[e * R_ + t]) * 0.1f;
      cs[t] = cosf(a);
      ss[t] = sinf(a);
    }
    const float* Pe = pw + (size_t)e * D_ * D_;
    __hip_bfloat16* We = Wb + (size_t)e * D_ * D_;
    float u = Pe[(size_t)(r0 + t) * D_];
    __syncthreads();
    for (int c = 0; c < 8; ++c) {
      for (int i = t; i < 256 * 16; i += 256) {
        int row = i >> 4, col = i & 15;
        Pch[row][col] = Pe[(size_t)(r0 + row) * D_ + 1 + 16 * c + col];
      }
      __syncthreads();
#pragma unroll
      for (int kk = 0; kk < 16; ++kk) {
        int k = 16 * c + kk;
        float pj = Pch[t][kk];
        Wch[t][kk] = __float2bfloat16(cs[k] * pj - ss[k] * u);
        u = cs[k] * u + ss[k] * pj;
      }
      __syncthreads();
      for (int i = t; i < 256 * 16; i += 256) {
        int row = i >> 4, col = i & 15;
        We[(size_t)(r0 + row) * D_ + 1 + 16 * c + col] = Wch[row][col];
      }
      __syncthreads();
    }
    We[(size_t)(r0 + t) * D_] = __float2bfloat16(u);
  } else if (blk < ROT_B + WT_B) {
    int g = (blk - ROT_B) * 256 + t;
    int gidx = g & 127;
    if (gidx < 32) return;
    float4 v = ((const float4*)pw)[g];
    union { short4 s; __hip_bfloat16 h[4]; } u;
    u.h[0] = __float2bfloat16(v.x);
    u.h[1] = __float2bfloat16(v.y);
    u.h[2] = __float2bfloat16(v.z);
    u.h[3] = __float2bfloat16(v.w);
    if (gidx > 32) {
      ((short4*)Wb)[g] = u.s;
    } else {
      Wb[(size_t)g * 4 + 1] = u.h[1];
      Wb[(size_t)g * 4 + 2] = u.h[2];
      Wb[(size_t)g * 4 + 3] = u.h[3];
    }
  } else {
    int i = (blk - ROT_B - WT_B) * 256 + t;
#pragma unroll
    for (int rep = 0; rep < 2; ++rep) {
      int idx = i + rep * (CX_B * 256);
      float4 v = ((const float4*)x)[idx];
      union { short4 s; __hip_bfloat16 h[4]; } u;
      u.h[0] = __float2bfloat16(v.x);
      u.h[1] = __float2bfloat16(v.y);
      u.h[2] = __float2bfloat16(v.z);
      u.h[3] = __float2bfloat16(v.w);
      ((short4*)xb)[idx] = u.s;
    }
  }
}

// ---------------------------------------------------------------------------
// GEMM: out[e] = Xb @ Wb[e]^T (NT). 256x256 tile, BK=64, NT(tiles)=8, 8 waves.
// 8-phase-style schedule: per K-tile, ALL 24 ds_read_b128 at phase 0 (frags
// held in regs), then 4 pure-MFMA quads (16 MFMA each) with one half-tile
// stage (2 gload_lds/wave) per phase. Half-slot rings (4 each for A and B).
// Counted vmcnt(6) at every tile boundary (never drains until the tail).
// Stage units aliasing this tile's read-slots are issued only after the
// __syncthreads() that drains p0's reads -> provably race-free.
// T1 XCD swizzle, T2 involutive chunk swizzle c^(row&7), T5 setprio.
// ---------------------------------------------------------------------------
__global__ __launch_bounds__(512, 2) void gemm_xw(
    const __hip_bfloat16* __restrict__ Xb,   // [M_TOT][512]
    const __hip_bfloat16* __restrict__ Wb,   // [E][512][512] rows=o, cols=d
    float* __restrict__ out)                 // [E][M_TOT][512]
{
  constexpr int BK = 64;
  constexpr int KD = D_, ND = D_;
  constexpr int NT = KD / BK;  // 8
  // 4 half-slots each: half = 128 rows x 64 k bf16 = 16 KB  -> 128 KB total
  __shared__ __align__(16) __hip_bfloat16 As[4][128 * 64];
  __shared__ __align__(16) __hip_bfloat16 Bs[4][128 * 64];

  // T1: bijective XCD-chunked swizzle, mt-major.
  int bx = blockIdx.x;                 // 1024 blocks
  int swz = (bx & 7) * 128 + (bx >> 3);
  int mt = swz >> 4;          // 0..63
  int e  = (swz >> 1) & 7;    // 0..7
  int nt = swz & 1;           // 0..1

  int tid = threadIdx.x;
  int wave = tid >> 6, lane = tid & 63;
  int lr = lane & 15, lk = lane >> 4;
  int wm = wave >> 2, wn = wave & 3;   // wave-tile 128x64 of C

  const __hip_bfloat16* Ag = Xb + (size_t)(mt * 256) * KD;
  const __hip_bfloat16* Bg = Wb + ((size_t)e * ND + (size_t)nt * 256) * KD;

  // staging: lane -> row l>>3 (8 rows/gload), chunk (l&7)^(l>>3) (involution,
  // within-row permutation -> full 128B-per-row coalescing kept)
  int srow = lane >> 3;
  int scol = ((lane & 7) ^ srow) * 8;  // bf16 elems

  // fragment read chunk terms: phys chunk = (kk*4+lk) ^ (lr&7)
  int axor0 = ((0 * 4 + lk) ^ (lr & 7)) * 8;
  int axor1 = ((1 * 4 + lk) ^ (lr & 7)) * 8;

  f32x4 acc[8][4];
#pragma unroll
  for (int i = 0; i < 8; ++i)
#pragma unroll
    for (int j = 0; j < 4; ++j) acc[i][j] = (f32x4){0.f, 0.f, 0.f, 0.f};

  // stage half h (128 rows) of tile tt for array ARR from GBASE
#define STAGE(ARR, GBASE, h, tt)                                             \
  {                                                                          \
    int slot_ = (2 * (tt) + (h)) & 3;                                        \
    _Pragma("unroll") for (int g = 0; g < 2; ++g) {                          \
      gload_lds16(&ARR[slot_][(wave * 16 + g * 8) * 64],                     \
                  (GBASE) + (size_t)((h) * 128 + wave * 16 + g * 8 + srow) * \
                                KD + (tt) * BK + scol);                      \
    }                                                                        \
  }

#define QUAD(mh, nh)                                                         \
  {                                                                          \
    __builtin_amdgcn_s_setprio(1);                                           \
    _Pragma("unroll") for (int m4 = 0; m4 < 4; ++m4)                         \
        _Pragma("unroll") for (int n2 = 0; n2 < 2; ++n2)                     \
            _Pragma("unroll") for (int kk = 0; kk < 2; ++kk)                 \
                acc[(mh)*4 + m4][(nh)*2 + n2] =                              \
                    __builtin_amdgcn_mfma_f32_16x16x32_bf16(                 \
                        af[(mh)*4 + m4][kk], bfr[(nh)*2 + n2][kk],           \
                        acc[(mh)*4 + m4][(nh)*2 + n2], 0, 0, 0);             \
    __builtin_amdgcn_s_setprio(0);                                           \
  }

  // prologue: 7 half-units (tile0 complete + A halves and B0 of tile1)
  STAGE(As, Ag, 0, 0); STAGE(As, Ag, 1, 0);
  STAGE(Bs, Bg, 0, 0); STAGE(Bs, Bg, 1, 0);
  STAGE(As, Ag, 0, 1); STAGE(As, Ag, 1, 1);
  STAGE(Bs, Bg, 0, 1);

#pragma unroll
  for (int t = 0; t < NT; ++t) {
    // tile t resident once <=6 newer half-unit loads remain in flight
    if (t < NT - 1) {
      asm volatile("s_waitcnt vmcnt(6)" ::: "memory");
    } else {
      asm volatile("s_waitcnt vmcnt(0)" ::: "memory");
    }
    __builtin_amdgcn_s_barrier();
    asm volatile("" ::: "memory");

    // ---- p0: all fragment reads (A 16, B 8 x b128) ----
    const __hip_bfloat16* Asl = As[(2 * t + wm) & 3];
    const __hip_bfloat16* Bsl = Bs[(2 * t + (wn >> 1)) & 3];
    bf16x8 af[8][2], bfr[4][2];
#pragma unroll
    for (int mi = 0; mi < 8; ++mi) {
      int rb = (mi * 16 + lr) * 64;
      af[mi][0] = *(const bf16x8*)&Asl[rb + axor0];
      af[mi][1] = *(const bf16x8*)&Asl[rb + axor1];
    }
#pragma unroll
    for (int ni = 0; ni < 4; ++ni) {
      int rb = ((wn & 1) * 64 + ni * 16 + lr) * 64;
      bfr[ni][0] = *(const bf16x8*)&Bsl[rb + axor0];
      bfr[ni][1] = *(const bf16x8*)&Bsl[rb + axor1];
    }
    if (t + 1 < NT) STAGE(Bs, Bg, 1, t + 1);  // slot (2t+3)&3: not read now
    __syncthreads();  // drains lgkm: p0 reads complete before p1+ stages land
    QUAD(0, 0);

    // ---- p1 ----
    if (t + 2 < NT) STAGE(As, Ag, 0, t + 2);
    asm volatile("" ::: "memory");
    __builtin_amdgcn_s_barrier();
    asm volatile("" ::: "memory");
    QUAD(0, 1);

    // ---- p2 ----
    if (t + 2 < NT) STAGE(As, Ag, 1, t + 2);
    asm volatile("" ::: "memory");
    __builtin_amdgcn_s_barrier();
    asm volatile("" ::: "memory");
    QUAD(1, 0);

    // ---- p3 ----
    if (t + 2 < NT) STAGE(Bs, Bg, 0, t + 2);
    asm volatile("" ::: "memory");
    __builtin_amdgcn_s_barrier();
    asm volatile("" ::: "memory");
    QUAD(1, 1);
  }
#undef STAGE
#undef QUAD

  // epilogue: C/D layout col = lane&15, row = (lane>>4)*4 + reg  [m89]
  size_t obase = (size_t)e * M_TOT * ND;
  int row0 = mt * 256 + wm * 128;
  int col0 = nt * 256 + wn * 64;
#pragma unroll
  for (int mi = 0; mi < 8; ++mi)
#pragma unroll
    for (int ni = 0; ni < 4; ++ni) {
      int r0 = row0 + mi * 16 + lk * 4;
      int c = col0 + ni * 16 + lr;
      float* op = out + obase + (size_t)r0 * ND + c;
#pragma unroll
      for (int q = 0; q < 4; ++q) op[(size_t)q * ND] = acc[mi][ni][q];
    }
}

extern "C" void kernel_launch(void* const* d_in, const int* in_sizes, int n_in,
                              void* d_out, int out_size, void* d_ws, size_t ws_size,
                              hipStream_t stream) {
  const float* x = (const float*)d_in[0];        // [B][S][D] f32
  const float* theta = (const float*)d_in[1];    // [E][R] f32
  const float* proj_w = (const float*)d_in[2];   // [E][D][D] f32
  float* out = (float*)d_out;                    // [E][B][S][D] f32

  __hip_bfloat16* xb = (__hip_bfloat16*)d_ws;                          // 16 MB
  __hip_bfloat16* Wb = (__hip_bfloat16*)((char*)d_ws +
                        (size_t)M_TOT * D_ * sizeof(__hip_bfloat16));  // 4 MB

  hipLaunchKernelGGL(prep_fused, dim3(ROT_B + WT_B + CX_B), dim3(256), 0,
                     stream, x, theta, proj_w, xb, Wb);
  hipLaunchKernelGGL(gemm_xw, dim3(E_ * (M_TOT / 256) * (D_ / 256)), dim3(512),
                     0, stream, xb, Wb, out);
}